// Round 2
// baseline (88.841 us; speedup 1.0000x reference)
//
#include <hip/hip_runtime.h>

// Problem constants: B=64, T=8192, L=64, NWIN=8128
// One block per batch: 64 blocks x 512 threads. Whole x-row staged in LDS
// (32 KB), each thread evaluates 16 consecutive windows from a register
// window-cache, block min-reduce on packed (dist,idx) u64 keys, then the SAME
// block gathers the winning 64-float window. No workspace, no atomics, no
// cross-block communication, single launch.
constexpr int B_SZ = 64;
constexpr int T_SZ = 8192;
constexpr int L_SZ = 64;
constexpr int NWIN = T_SZ - L_SZ;    // 8128
constexpr int NTHR = 512;
constexpr int WPT  = 16;             // windows per thread; 508 active threads (508*16=8128)

// XOR swizzle on float4 index: involution (applies identically on store and
// load), spreads stride-4 float4 reads across all eight 16B bank-slots so each
// wave's ds_read_b128 lands at the 8-lanes-per-slot LDS bandwidth floor
// instead of a 32-way conflict.
__device__ __forceinline__ int swz(int i) { return i ^ ((i >> 3) & 7); }

__global__ __launch_bounds__(NTHR, 2)
void window_match_one(const float* __restrict__ X_in,
                      const float* __restrict__ X_out,
                      float* __restrict__ out)
{
    __shared__ float xs[T_SZ];                 // 32 KB, swizzled float4 layout
    __shared__ float ysh[L_SZ];
    __shared__ unsigned long long wred[NTHR / 64];
    __shared__ int s_win;

    const int b   = blockIdx.x;
    const int tid = threadIdx.x;

    // Stage full row: 2048 float4 over 512 threads = 4 per thread.
    // Global side stays linear/coalesced; LDS side permuted by swz.
    const float4* xg  = reinterpret_cast<const float4*>(X_in + (size_t)b * T_SZ);
    float4*       xs4 = reinterpret_cast<float4*>(xs);
    #pragma unroll
    for (int r = 0; r < T_SZ / 4 / NTHR; ++r) {      // 4 rounds
        const int i = tid + r * NTHR;
        xs4[swz(i)] = xg[i];
    }
    if (tid < L_SZ) ysh[tid] = X_out[(size_t)b * L_SZ + tid];
    __syncthreads();

    // y broadcast into registers (same-address LDS reads = free broadcast)
    float y[L_SZ];
    #pragma unroll
    for (int j = 0; j < L_SZ; ++j) y[j] = ysh[j];

    unsigned long long best = ~0ull;
    const int s0 = WPT * tid;                        // first window of this thread
    if (s0 < NWIN) {                                 // tid < 508
        // Register cache of xs[s0 .. s0+79]: 20 swizzled b128 reads.
        float xv[WPT + L_SZ];                        // 80 floats
        const float4* xr = reinterpret_cast<const float4*>(xs);
        #pragma unroll
        for (int i = 0; i < (WPT + L_SZ) / 4; ++i) { // 20
            const float4 v = xr[swz(4 * tid + i)];
            xv[4 * i + 0] = v.x;
            xv[4 * i + 1] = v.y;
            xv[4 * i + 2] = v.z;
            xv[4 * i + 3] = v.w;
        }
        // 16 windows, fully unrolled (static register indexing only).
        // Packed key: ((float_bits(d)<<32)|idx) — d>=0 so u64 order ==
        // (dist, idx) lexicographic, ties -> smallest index == np.argmin.
        #pragma unroll
        for (int w = 0; w < WPT; ++w) {
            float d = 0.0f;
            #pragma unroll
            for (int j = 0; j < L_SZ; ++j) {
                const float t = xv[w + j] - y[j];
                d = fmaf(t, t, d);
            }
            const unsigned long long key =
                ((unsigned long long)__float_as_uint(d) << 32) |
                (unsigned int)(s0 + w);
            best = key < best ? key : best;
        }
    }

    // Wave (64-lane) shuffle reduce, then cross-wave (8 waves) via LDS.
    #pragma unroll
    for (int off = 32; off > 0; off >>= 1) {
        const unsigned long long o = __shfl_down(best, off, 64);
        best = o < best ? o : best;
    }
    if ((tid & 63) == 0) wred[tid >> 6] = best;
    __syncthreads();

    if (tid == 0) {
        unsigned long long m = wred[0];
        #pragma unroll
        for (int wv = 1; wv < NTHR / 64; ++wv) {
            const unsigned long long o = wred[wv];
            m = o < m ? o : m;
        }
        s_win = (int)(m & 0xffffffffu);
    }
    __syncthreads();

    // Same block gathers: bit-exact copy of the winning window from global.
    if (tid < L_SZ)
        out[(size_t)b * L_SZ + tid] = X_in[(size_t)b * T_SZ + s_win + tid];
}

extern "C" void kernel_launch(void* const* d_in, const int* in_sizes, int n_in,
                              void* d_out, int out_size, void* d_ws, size_t ws_size,
                              hipStream_t stream) {
    // Input order: feats_in (unused), X_in, feats_out (unused), X_out
    const float* X_in  = (const float*)d_in[1];
    const float* X_out = (const float*)d_in[3];
    float* out = (float*)d_out;

    window_match_one<<<B_SZ, NTHR, 0, stream>>>(X_in, X_out, out);
}